// Round 8
// baseline (745.092 us; speedup 1.0000x reference)
//
#include <hip/hip_runtime.h>
#include <hip/hip_bf16.h>

#define BB 8
#define TT 168
#define NN 425
#define EE 2048
#define II 128
#define HH 256
#define F1 10
#define F2 32
#define BT (BB*TT)       // 1344
#define K2 (NN*F2)       // 13600
#define N2 (2*NN)        // 850

// MFMA LSTM fragment bookkeeping:
// wave w owns gates n in [128w,128w+128) as 8 tiles of 16 (j=0..7), K=256 as
// 8 chunks of 32 (kc=0..7). B-frag(j,kc) lane l = Whh[128w+16j+(l&15)]
// [32kc+8(l>>4) .. +8] as 8 fp16 (4 regs). Residency: j<7 -> kc<6 in regs,
// j==7 -> kc<4 in regs; rest in LDS. 46 reg-frags (184 regs), 18 LDS-frags.
#define BREG_PW 46
#define BLDS_PW 18
#define BREG_N (8*BREG_PW*64)   // 23552 h8
#define BLDS_N (8*BLDS_PW*64)   // 9216 h8 = 144 KB

typedef _Float16 h2 __attribute__((ext_vector_type(2)));
typedef _Float16 h8 __attribute__((ext_vector_type(8)));
typedef short bf16x8 __attribute__((ext_vector_type(8)));
typedef float f32x4 __attribute__((ext_vector_type(4)));

__device__ __forceinline__ float relu_(float x){ return fmaxf(x, 0.f); }
__device__ __forceinline__ float sigmoid_(float x){ return 1.f/(1.f + expf(-x)); }

// ---------------- GCN: two layers fused, one block per (b,t) graph ----------
__global__ __launch_bounds__(256) void gcn_kernel(
    const float* __restrict__ nf, const int* __restrict__ esrc,
    const int* __restrict__ edst, const float* __restrict__ ew,
    const float* __restrict__ Wg1, const float* __restrict__ bg1,
    const float* __restrict__ Wg2, const float* __restrict__ bg2,
    __hip_bfloat16* __restrict__ x2g)
{
    __shared__ float xs[NN];
    __shared__ float dinv[NN];
    __shared__ float agg1[NN];
    __shared__ float nrm[EE];
    __shared__ float x1[NN*F1];
    __shared__ float agg2[NN*F1];
    __shared__ float wg1s[F1], bg1s[F1], wg2s[F1*F2], bg2s[F2];

    const int bt = blockIdx.x, tid = threadIdx.x;
    const long eb = (long)bt * EE;

    for (int v = tid; v < NN; v += 256) {
        xs[v] = nf[(long)bt*NN + v];
        dinv[v] = 1.0f;
        agg1[v] = 0.f;
    }
    for (int i = tid; i < NN*F1; i += 256) agg2[i] = 0.f;
    if (tid < F1) { wg1s[tid] = Wg1[tid]; bg1s[tid] = bg1[tid]; }
    if (tid < F2) bg2s[tid] = bg2[tid];
    for (int i = tid; i < F1*F2; i += 256) wg2s[i] = Wg2[i];
    __syncthreads();

    for (int e = tid; e < EE; e += 256)
        atomicAdd(&dinv[edst[eb+e]], ew[eb+e]);
    __syncthreads();
    for (int v = tid; v < NN; v += 256) {
        float dg = dinv[v];
        dinv[v] = dg > 0.f ? 1.0f / sqrtf(fmaxf(dg, 1e-12f)) : 0.f;
    }
    __syncthreads();

    for (int e = tid; e < EE; e += 256) {
        int s = esrc[eb+e], d = edst[eb+e];
        float nm = dinv[s] * ew[eb+e] * dinv[d];
        nrm[e] = nm;
        atomicAdd(&agg1[d], nm * xs[s]);
    }
    __syncthreads();
    for (int v = tid; v < NN; v += 256) agg1[v] += dinv[v]*dinv[v]*xs[v];
    __syncthreads();
    for (int i = tid; i < NN*F1; i += 256) {
        int v = i / F1, f = i - v*F1;
        x1[i] = relu_(agg1[v] * wg1s[f] + bg1s[f]);
    }
    __syncthreads();

    for (int e = tid; e < EE; e += 256) {
        int s = esrc[eb+e], d = edst[eb+e];
        float nm = nrm[e];
        #pragma unroll
        for (int f = 0; f < F1; ++f)
            atomicAdd(&agg2[d*F1+f], nm * x1[s*F1+f]);
    }
    __syncthreads();
    for (int i = tid; i < NN*F1; i += 256) {
        int v = i / F1;
        agg2[i] += dinv[v]*dinv[v]*x1[i];
    }
    __syncthreads();

    for (int i = tid; i < NN*F2; i += 256) {
        int v = i >> 5, k = i & 31;
        float o = bg2s[k];
        #pragma unroll
        for (int f = 0; f < F1; ++f) o += agg2[v*F1+f] * wg2s[f*F2+k];
        x2g[(long)bt*K2 + i] = __float2bfloat16(relu_(o));
    }
}

// ---------------- transpose-pack Wgfc fp32 [13600,128] -> bf16 [128,13600] --
__global__ __launch_bounds__(256) void packT_kernel(
    const float* __restrict__ W, __hip_bfloat16* __restrict__ out)
{
    __shared__ float tile[64][129];
    const int k0 = blockIdx.x * 64, tid = threadIdx.x;
    for (int i = tid; i < 64*128; i += 256) {
        int r = i >> 7, j = i & 127;
        tile[r][j] = (k0 + r < K2) ? W[(size_t)(k0+r)*II + j] : 0.f;
    }
    __syncthreads();
    for (int i = tid; i < 64*128; i += 256) {
        int j = i >> 6, r = i & 63;
        if (k0 + r < K2) out[(size_t)j*K2 + k0 + r] = __float2bfloat16(tile[r][j]);
    }
}

// ---------------- MFMA bf16 GEMM, split-K: g_pre += x2 @ Wgfc ---------------
#define GBM 64
#define GBK 64
#define GCH 8
#define GST 27
__global__ __launch_bounds__(256) void gemm_kernel(
    const __hip_bfloat16* __restrict__ A, const __hip_bfloat16* __restrict__ Bt,
    float* __restrict__ C)
{
    __shared__ __align__(16) char As[2][GBM*GBK*2];
    __shared__ __align__(16) char Bs[2][II*GBK*2];
    const int tid = threadIdx.x;
    const int row0 = blockIdx.x * GBM;
    const int kbeg = blockIdx.y * (GST*GBK);
    const int wave = tid >> 6, lane = tid & 63;
    const int wm = wave >> 1, wn = wave & 1;
    const int l16 = lane & 15, lk = lane >> 4;
    const short* Aa = (const short*)A;
    const short* Bb = (const short*)Bt;

    const int ar = tid >> 2, ac = tid & 3;
    const int bc = tid >> 1, bh = (tid & 1) * 4;

    f32x4 acc[2][4];
    #pragma unroll
    for (int m = 0; m < 2; ++m)
        #pragma unroll
        for (int n = 0; n < 4; ++n) acc[m][n] = (f32x4){0.f,0.f,0.f,0.f};

    {
        #pragma unroll
        for (int j = 0; j < 2; ++j) {
            bf16x8 va = {0,0,0,0,0,0,0,0};
            int k = kbeg + ac*16 + j*8;
            if (k < K2) va = *(const bf16x8*)(Aa + (size_t)(row0+ar)*K2 + k);
            *(bf16x8*)(&As[0][0] + ((ar*128 + (ac*2+j)*16) ^ ((ar&7)<<4))) = va;
        }
        #pragma unroll
        for (int j = 0; j < 4; ++j) {
            bf16x8 vb = {0,0,0,0,0,0,0,0};
            int k = kbeg + (bh+j)*8;
            if (k < K2) vb = *(const bf16x8*)(Bb + (size_t)bc*K2 + k);
            *(bf16x8*)(&Bs[0][0] + ((bc*128 + (bh+j)*16) ^ ((bc&7)<<4))) = vb;
        }
    }
    __syncthreads();

    for (int s = 0; s < GST; ++s) {
        const int d = s & 1;
        bf16x8 pa[2], pb[4];
        #pragma unroll
        for (int j = 0; j < 2; ++j) pa[j] = (bf16x8){0,0,0,0,0,0,0,0};
        #pragma unroll
        for (int j = 0; j < 4; ++j) pb[j] = (bf16x8){0,0,0,0,0,0,0,0};
        if (s + 1 < GST) {
            int k0n = kbeg + (s+1)*GBK;
            #pragma unroll
            for (int j = 0; j < 2; ++j) {
                int k = k0n + ac*16 + j*8;
                if (k < K2) pa[j] = *(const bf16x8*)(Aa + (size_t)(row0+ar)*K2 + k);
            }
            #pragma unroll
            for (int j = 0; j < 4; ++j) {
                int k = k0n + (bh+j)*8;
                if (k < K2) pb[j] = *(const bf16x8*)(Bb + (size_t)bc*K2 + k);
            }
        }
        #pragma unroll
        for (int s2 = 0; s2 < 2; ++s2) {
            bf16x8 af[2], bf[4];
            #pragma unroll
            for (int m = 0; m < 2; ++m) {
                int row = wm*32 + m*16 + l16;
                af[m] = *(const bf16x8*)(&As[d][0] + ((row*128 + s2*64 + lk*16) ^ ((row&7)<<4)));
            }
            #pragma unroll
            for (int n = 0; n < 4; ++n) {
                int col = wn*64 + n*16 + l16;
                bf[n] = *(const bf16x8*)(&Bs[d][0] + ((col*128 + s2*64 + lk*16) ^ ((col&7)<<4)));
            }
            #pragma unroll
            for (int m = 0; m < 2; ++m)
                #pragma unroll
                for (int n = 0; n < 4; ++n)
                    acc[m][n] = __builtin_amdgcn_mfma_f32_16x16x32_bf16(af[m], bf[n], acc[m][n], 0, 0, 0);
        }
        if (s + 1 < GST) {
            #pragma unroll
            for (int j = 0; j < 2; ++j)
                *(bf16x8*)(&As[d^1][0] + ((ar*128 + (ac*2+j)*16) ^ ((ar&7)<<4))) = pa[j];
            #pragma unroll
            for (int j = 0; j < 4; ++j)
                *(bf16x8*)(&Bs[d^1][0] + ((bc*128 + (bh+j)*16) ^ ((bc&7)<<4))) = pb[j];
        }
        __syncthreads();
    }

    #pragma unroll
    for (int m = 0; m < 2; ++m)
        #pragma unroll
        for (int n = 0; n < 4; ++n)
            #pragma unroll
            for (int q = 0; q < 4; ++q)
                atomicAdd(&C[(size_t)(row0 + wm*32 + m*16 + lk*4 + q)*II + wn*64 + n*16 + l16],
                          acc[m][n][q]);
}

// ---------------- infect & temp MLP branches (16 rows per block) ------------
__global__ __launch_bounds__(256) void branches_kernel(
    const float* __restrict__ infect, const float* __restrict__ temp,
    const float* __restrict__ Wi1, const float* __restrict__ bi1,
    const float* __restrict__ Wi2, const float* __restrict__ bi2,
    const float* __restrict__ Wi3, const float* __restrict__ bi3,
    const float* __restrict__ Wi4, const float* __restrict__ bi4,
    const float* __restrict__ Wt1, const float* __restrict__ bt1,
    const float* __restrict__ Wt2, const float* __restrict__ bt2,
    float* __restrict__ infout, float* __restrict__ tpout)
{
    __shared__ float inA[16*25], inT[16*13];
    __shared__ float bufA[16*II], bufB[16*II];
    const int r0 = blockIdx.x * 16, tid = threadIdx.x;

    for (int i = tid; i < 16*25; i += 256) { int r=i/25,k=i-r*25; inA[i] = infect[(long)(r0+r)*25+k]; }
    for (int i = tid; i < 16*13; i += 256) { int r=i/13,k=i-r*13; inT[i] = temp[(long)(r0+r)*13+k]; }
    __syncthreads();
    for (int i = tid; i < 16*II; i += 256) { int r=i>>7,u=i&127; float o=bi1[u];
        for (int k=0;k<25;++k) o += inA[r*25+k]*Wi1[k*II+u];
        bufA[i]=relu_(o); }
    __syncthreads();
    for (int i = tid; i < 16*II; i += 256) { int r=i>>7,u=i&127; float o=bi2[u];
        for (int k=0;k<II;++k) o += bufA[r*II+k]*Wi2[k*II+u];
        bufB[i]=relu_(o); }
    __syncthreads();
    for (int i = tid; i < 16*64; i += 256) { int r=i>>6,u=i&63; float o=bi3[u];
        for (int k=0;k<II;++k) o += bufB[r*II+k]*Wi3[k*64+u];
        bufA[r*64+u]=relu_(o); }
    __syncthreads();
    for (int i = tid; i < 16*II; i += 256) { int r=i>>7,u=i&127; float o=bi4[u];
        for (int k=0;k<64;++k) o += bufA[r*64+k]*Wi4[k*II+u];
        infout[(long)(r0+r)*II+u]=relu_(o); }
    for (int i = tid; i < 16*64; i += 256) { int r=i>>6,u=i&63; float o=bt1[u];
        for (int k=0;k<13;++k) o += inT[r*13+k]*Wt1[k*64+u];
        bufB[r*64+u]=relu_(o); }
    __syncthreads();
    for (int i = tid; i < 16*II; i += 256) { int r=i>>7,u=i&127; float o=bt2[u];
        for (int k=0;k<64;++k) o += bufB[r*64+k]*Wt2[k*II+u];
        tpout[(long)(r0+r)*II+u]=relu_(o); }
}

// ---------------- li = relu(cat@Wcat+bcat); xg = li@Wih^T + bih + bhh -------
__global__ __launch_bounds__(256) void li_xg_kernel(
    const float* __restrict__ g_pre, const float* __restrict__ bgfc,
    const float* __restrict__ infb, const float* __restrict__ tpb,
    const float* __restrict__ Wcat, const float* __restrict__ bcat,
    const float* __restrict__ Wih, const float* __restrict__ bih,
    const float* __restrict__ bhh, float* __restrict__ xg)
{
    __shared__ float cat[16*384];
    __shared__ __align__(16) float li[16*II];
    const int r0 = blockIdx.x * 16, tid = threadIdx.x;

    for (int i = tid; i < 16*II; i += 256) {
        int r = i>>7, u = i&127;
        cat[r*384 + u]       = relu_(g_pre[(long)(r0+r)*II+u] + bgfc[u]);
        cat[r*384 + 128 + u] = infb[(long)(r0+r)*II+u];
        cat[r*384 + 256 + u] = tpb[(long)(r0+r)*II+u];
    }
    __syncthreads();
    {
        int u = tid & 127, rh = tid >> 7;
        float acc[8];
        #pragma unroll
        for (int x = 0; x < 8; ++x) acc[x] = bcat[u];
        for (int k = 0; k < 384; ++k) {
            float w = Wcat[k*II+u];
            #pragma unroll
            for (int x = 0; x < 8; ++x) acc[x] += cat[(rh*8+x)*384 + k] * w;
        }
        #pragma unroll
        for (int x = 0; x < 8; ++x) li[(rh*8+x)*II + u] = relu_(acc[x]);
    }
    __syncthreads();
    for (int jj = 0; jj < 4; ++jj) {
        int j = tid + jj*256;
        float bb = bih[j] + bhh[j];
        float acc[16];
        #pragma unroll
        for (int r = 0; r < 16; ++r) acc[r] = bb;
        for (int k4 = 0; k4 < 32; ++k4) {
            float4 wv = *(const float4*)&Wih[(long)j*II + k4*4];
            #pragma unroll
            for (int r = 0; r < 16; ++r) {
                float4 lv = *(const float4*)&li[r*II + k4*4];
                acc[r] += wv.x*lv.x + wv.y*lv.y + wv.z*lv.z + wv.w*lv.w;
            }
        }
        #pragma unroll
        for (int r = 0; r < 16; ++r) xg[(long)(r0+r)*1024 + j] = acc[r];
    }
}

// ---------------- pack Whh fp32 -> fp16 MFMA B-fragments --------------------
// bregp[(w*46 + fidx)*64 + lane], fidx: j<7 -> j*6+kc (kc<6); j==7 -> 42+kc (kc<4)
// bldsp[(w*18 + fidx)*64 + lane], fidx: j<7 -> j*2+(kc-6); j==7 -> 14+(kc-4)
// frag lane l: Whh row 128w+16j+(l&15), k = 32kc+8*(l>>4) .. +8  (fp32->fp16)
__global__ __launch_bounds__(256) void pack_whh_kernel(
    const float* __restrict__ Whh, h8* __restrict__ bregp,
    h8* __restrict__ bldsp)
{
    int i = blockIdx.x*256 + threadIdx.x;    // 128 blocks -> 32768 = 23552+9216
    int w, j, kc, lane;
    bool isreg = (i < BREG_N);
    if (isreg) {
        w = i / (BREG_PW*64); int r = i % (BREG_PW*64);
        int fidx = r >> 6; lane = r & 63;
        j  = (fidx < 42) ? fidx / 6 : 7;
        kc = (fidx < 42) ? fidx % 6 : fidx - 42;
    } else {
        int L = i - BREG_N;
        if (L >= BLDS_N) return;
        w = L / (BLDS_PW*64); int r = L % (BLDS_PW*64);
        int fidx = r >> 6; lane = r & 63;
        j  = (fidx < 14) ? (fidx >> 1) : 7;
        kc = (fidx < 14) ? 6 + (fidx & 1) : 4 + (fidx - 14);
    }
    int row = 128*w + 16*j + (lane & 15);
    int col = 32*kc + 8*(lane >> 4);
    h8 v;
    #pragma unroll
    for (int e = 0; e < 8; ++e) v[e] = (_Float16)Whh[(long)row*HH + col + e];
    if (isreg) bregp[i] = v; else bldsp[i - BREG_N] = v;
}

// ---------------- LSTM: 1 block/batch, MFMA, weights in regs (no asm pin) ---
__attribute__((amdgpu_waves_per_eu(2, 2)))
__global__ __launch_bounds__(512) void lstm_kernel(
    const float* __restrict__ xg, const h8* __restrict__ bregp,
    const h8* __restrict__ bldsp, const float* __restrict__ h0,
    const float* __restrict__ c0, float* __restrict__ hbuf)
{
    const int u = threadIdx.x;
    const int lane = u & 63;
    const int w = u >> 6;
    const int b = blockIdx.x;

    __shared__ __align__(16) h8 wlds[BLDS_N];        // 144 KB
    __shared__ float gbuf[1024];                     // 4 KB
    __shared__ __align__(16) _Float16 harr[2][HH];   // 1 KB

    for (int i = u; i < BLDS_N; i += 512) wlds[i] = bldsp[i];

    h8 bfr[BREG_PW];                                 // 184 regs (VGPR/AGPR)
    {
        const h8* bp = bregp + (size_t)(w*BREG_PW)*64 + lane;
        #pragma unroll
        for (int m = 0; m < BREG_PW; ++m) bfr[m] = bp[(size_t)m*64];
    }

    float c = 0.f, h_last = 0.f;
    if (u < 256) { c = c0[b*HH + u]; harr[0][u] = (_Float16)h0[b*HH + u]; }
    __syncthreads();

    const float* xgb = xg + (size_t)b*TT*1024;
    const char* wbase = (const char*)wlds + w*(BLDS_PW*1024);
    const char* hbase = (const char*)harr;
    const int q16 = (lane >> 4) << 4;

    #pragma unroll 1
    for (int t = 0; t < TT; ++t) {
        const int cb = t & 1;
        float x0 = 0.f, x1 = 0.f, x2 = 0.f, x3 = 0.f;
        if (u < 256) {
            x0 = xgb[t*1024 + u];        x1 = xgb[t*1024 + 256 + u];
            x2 = xgb[t*1024 + 512 + u];  x3 = xgb[t*1024 + 768 + u];
        }
        h8 a[8];
        #pragma unroll
        for (int kc = 0; kc < 8; ++kc)
            a[kc] = *(const h8*)(hbase + cb*512 + kc*64 + q16);

        #pragma unroll
        for (int j = 0; j < 8; ++j) {
            f32x4 acc = (f32x4){0.f, 0.f, 0.f, 0.f};
            #pragma unroll
            for (int kc = 0; kc < 8; ++kc) {
                h8 bv;
                if ((j < 7) ? (kc < 6) : (kc < 4)) {
                    bv = bfr[(j < 7) ? (j*6 + kc) : (42 + kc)];
                } else {
                    unsigned off = (unsigned)(((j < 7) ? (j*2 + kc - 6)
                                                       : (14 + kc - 4))*1024 + lane*16);
                    asm volatile("" : "+v"(off));   // opaque: keep read in-loop
                    bv = *(const h8*)(wbase + off);
                }
                acc = __builtin_amdgcn_mfma_f32_16x16x32_f16(a[kc], bv, acc, 0, 0, 0);
            }
            if (lane < 16) gbuf[w*128 + j*16 + lane] = acc[0];   // D row 0
        }
        __syncthreads();
        if (u < 256) {
            float gi = gbuf[u]       + x0;
            float gf = gbuf[256 + u] + x1;
            float gg = gbuf[512 + u] + x2;
            float go = gbuf[768 + u] + x3;
            c = sigmoid_(gf)*c + sigmoid_(gi)*tanhf(gg);
            float h = sigmoid_(go)*tanhf(c);
            harr[cb ^ 1][u] = (_Float16)h;
            h_last = h;
        }
        __syncthreads();
    }
    if (u < 256) hbuf[b*HH + u] = h_last;
}

// ---------------- final FC: out = relu(relu(h_T) @ Wfc + bfc) ---------------
__global__ __launch_bounds__(256) void final_fc_kernel(
    const float* __restrict__ hbuf, const float* __restrict__ Wfc,
    const float* __restrict__ bfc, float* __restrict__ out)
{
    int idx = blockIdx.x*256 + threadIdx.x;
    if (idx >= BB*N2) return;
    int b = idx / N2, j = idx - b*N2;
    const float* h = hbuf + b*HH;
    float o = bfc[j];
    for (int k = 0; k < HH; ++k) o += fmaxf(h[k], 0.f) * Wfc[(long)k*N2 + j];
    out[idx] = relu_(o);
}

extern "C" void kernel_launch(void* const* d_in, const int* in_sizes, int n_in,
                              void* d_out, int out_size, void* d_ws, size_t ws_size,
                              hipStream_t stream) {
    const float* nf     = (const float*)d_in[0];
    const int*   esrc   = (const int*)d_in[1];
    const int*   edst   = (const int*)d_in[2];
    const float* ew     = (const float*)d_in[3];
    const float* infect = (const float*)d_in[4];
    const float* temp   = (const float*)d_in[5];
    const float* h0     = (const float*)d_in[6];
    const float* c0     = (const float*)d_in[7];
    const float* Wg1    = (const float*)d_in[8];
    const float* bg1    = (const float*)d_in[9];
    const float* Wg2    = (const float*)d_in[10];
    const float* bg2    = (const float*)d_in[11];
    const float* Wgfc   = (const float*)d_in[12];
    const float* bgfc   = (const float*)d_in[13];
    const float* Wi1    = (const float*)d_in[14];
    const float* bi1    = (const float*)d_in[15];
    const float* Wi2    = (const float*)d_in[16];
    const float* bi2    = (const float*)d_in[17];
    const float* Wi3    = (const float*)d_in[18];
    const float* bi3    = (const float*)d_in[19];
    const float* Wi4    = (const float*)d_in[20];
    const float* bi4    = (const float*)d_in[21];
    const float* Wt1    = (const float*)d_in[22];
    const float* bt1    = (const float*)d_in[23];
    const float* Wt2    = (const float*)d_in[24];
    const float* bt2    = (const float*)d_in[25];
    const float* Wcat   = (const float*)d_in[26];
    const float* bcat   = (const float*)d_in[27];
    const float* Wih    = (const float*)d_in[28];
    const float* Whh    = (const float*)d_in[29];
    const float* bih    = (const float*)d_in[30];
    const float* bhh    = (const float*)d_in[31];
    const float* Wfc    = (const float*)d_in[32];
    const float* bfc    = (const float*)d_in[33];

    char* ws = (char*)d_ws;
    size_t off = 0;
    __hip_bfloat16* x2g = (__hip_bfloat16*)(ws + off); off += (size_t)BT*K2*2;
    __hip_bfloat16* WgfcT = (__hip_bfloat16*)(ws + off); off += (size_t)II*K2*2;
    float* g_pre = (float*)(ws + off); off += (size_t)BT*II*4;
    float* infb  = (float*)(ws + off); off += (size_t)BT*II*4;
    float* tpb   = (float*)(ws + off); off += (size_t)BT*II*4;
    float* xg    = (float*)(ws + off); off += (size_t)BT*1024*4;
    float* hbuf  = (float*)(ws + off); off += (size_t)BB*HH*4;
    h8* bregp = (h8*)(ws + off); off += (size_t)BREG_N*16;
    h8* bldsp = (h8*)(ws + off); off += (size_t)BLDS_N*16;

    hipMemsetAsync(g_pre, 0, (size_t)BT*II*4, stream);

    pack_whh_kernel<<<128, 256, 0, stream>>>(Whh, bregp, bldsp);
    packT_kernel<<<(K2 + 63)/64, 256, 0, stream>>>(Wgfc, WgfcT);
    gcn_kernel<<<BT, 256, 0, stream>>>(nf, esrc, edst, ew, Wg1, bg1, Wg2, bg2, x2g);
    branches_kernel<<<BT/16, 256, 0, stream>>>(infect, temp, Wi1, bi1, Wi2, bi2,
                                               Wi3, bi3, Wi4, bi4, Wt1, bt1, Wt2, bt2,
                                               infb, tpb);
    gemm_kernel<<<dim3(BT/GBM, GCH), 256, 0, stream>>>(x2g, WgfcT, g_pre);
    li_xg_kernel<<<BT/16, 256, 0, stream>>>(g_pre, bgfc, infb, tpb, Wcat, bcat,
                                            Wih, bih, bhh, xg);
    lstm_kernel<<<BB, 512, 0, stream>>>(xg, bregp, bldsp, h0, c0, hbuf);
    final_fc_kernel<<<(BB*N2 + 255)/256, 256, 0, stream>>>(hbuf, Wfc, bfc, (float*)d_out);
}